// Round 2
// baseline (606.718 us; speedup 1.0000x reference)
//
#include <hip/hip_runtime.h>
#include <hip/hip_bf16.h>

// Single-head self-attention, B=8 S=2048 E=768, fp32 in/out.
// R2: R1 + global_load_lds width=16 async staging (m93->m97 ladder rung).
//   gemm_bt staging: each wave stages k-chunk==wave, halves 0/1, for A and B.
//   LDS layout (fragment-major [kchunk][row][8]) is unchanged and is exactly
//   the wave-uniform-base + lane*16 contiguous order global_load_lds requires.

using short8  = __attribute__((ext_vector_type(8))) short;
using floatx4 = __attribute__((ext_vector_type(4))) float;

typedef const __attribute__((address_space(1))) unsigned short* gas_us;
typedef __attribute__((address_space(3))) unsigned short* las_us;

__device__ __forceinline__ float bf2f(unsigned short u){
  union { unsigned int i; float f; } v; v.i = ((unsigned int)u) << 16; return v.f;
}
__device__ __forceinline__ unsigned short f2bf(float f){
  union { float f; unsigned int i; } v; v.f = f;
  unsigned int r = v.i + 0x7fffu + ((v.i >> 16) & 1u);   // RNE
  return (unsigned short)(r >> 16);
}

// ---------------- prep kernels ----------------

__global__ __launch_bounds__(256) void cast_f32_bf16(const float* __restrict__ in,
                                                     unsigned short* __restrict__ out,
                                                     long n){
  long i = ((long)blockIdx.x * 256 + threadIdx.x) * 4;
  if (i + 3 < n) {
    float4 v = *(const float4*)(in + i);
    uint2 o;
    o.x = (unsigned int)f2bf(v.x) | ((unsigned int)f2bf(v.y) << 16);
    o.y = (unsigned int)f2bf(v.z) | ((unsigned int)f2bf(v.w) << 16);
    *(uint2*)(out + i) = o;
  }
}

// W [n x n] fp32 row-major -> Wt [n x n] bf16, Wt[f][e] = W[e][f]
__global__ __launch_bounds__(256) void transpose_cast_w(const float* __restrict__ W,
                                                        unsigned short* __restrict__ Wt,
                                                        int n){
  __shared__ float tile[64][65];
  int bx = blockIdx.x * 64;     // f base
  int by = blockIdx.y * 64;     // e base
  int tx = threadIdx.x & 63;
  int ty = threadIdx.x >> 6;    // 0..3
  #pragma unroll
  for (int r = ty; r < 64; r += 4)
    tile[r][tx] = W[(long)(by + r) * n + bx + tx];
  __syncthreads();
  #pragma unroll
  for (int r = ty; r < 64; r += 4)
    Wt[(long)(bx + r) * n + by + tx] = f2bf(tile[tx][r]);
}

// ---------------- tiled MFMA GEMM ----------------
// C[m,n] = alpha * sum_k A[m,k]*Bt[n,k]  (+ bias)
// A  : bf16 [M,K] row-major (batch stride sA elements)
// Bt : bf16 [N,K] row-major (batch stride sB elements)
// C  : bf16 or fp32, ldc leading dim (batch stride sC elements)
// M,N multiples of 128; K multiple of 32. No bounds checks.

#define BM 128
#define BN 128
#define BK 32

__global__ __launch_bounds__(256) void gemm_bt(
    const unsigned short* __restrict__ A,
    const unsigned short* __restrict__ Bt,
    void* __restrict__ Cout,
    const float* __restrict__ bias,
    int M, int N, int K, int ldc,
    long sA, long sB, long sC,
    float alpha, int bias_mode, int out_fp32)
{
  const int bz = blockIdx.z;
  A  += (long)bz * sA;
  Bt += (long)bz * sB;

  // fragment-major LDS: [k-chunk 0..3][row 0..127][8 bf16]
  __shared__ __align__(16) unsigned short Asm[4 * BM * 8];
  __shared__ __align__(16) unsigned short Bsm[4 * BN * 8];

  const int tid  = threadIdx.x;
  const int wave = tid >> 6;
  const int lane = tid & 63;
  const int la   = lane & 15;
  const int quad = lane >> 4;
  const int wm = (wave & 1) * 64;
  const int wn = (wave >> 1) * 64;

  const long m0 = (long)blockIdx.y * BM;
  const long n0 = (long)blockIdx.x * BN;

  // staging (async direct-to-LDS): wave w stages k-chunk w, halves c=0/1.
  // lane i lands at LDS unit (w*128 + c*64 + i) == layout row r=c*64+i.
  const unsigned short* gA = A  + (m0 + lane) * (long)K + wave * 8;
  const unsigned short* gB = Bt + (n0 + lane) * (long)K + wave * 8;
  las_us ldsA0 = (las_us)&Asm[(wave * BM +  0) * 8];
  las_us ldsA1 = (las_us)&Asm[(wave * BM + 64) * 8];
  las_us ldsB0 = (las_us)&Bsm[(wave * BN +  0) * 8];
  las_us ldsB1 = (las_us)&Bsm[(wave * BN + 64) * 8];
  const long rowoff = 64 * (long)K;

  floatx4 acc[4][4];
  #pragma unroll
  for (int i = 0; i < 4; i++)
    #pragma unroll
    for (int j = 0; j < 4; j++)
      #pragma unroll
      for (int r = 0; r < 4; r++) acc[i][j][r] = 0.0f;

  const short8* Asm8 = (const short8*)Asm;
  const short8* Bsm8 = (const short8*)Bsm;

  for (int k0 = 0; k0 < K; k0 += BK) {
    __builtin_amdgcn_global_load_lds((gas_us)(gA + k0),          ldsA0, 16, 0, 0);
    __builtin_amdgcn_global_load_lds((gas_us)(gA + k0 + rowoff), ldsA1, 16, 0, 0);
    __builtin_amdgcn_global_load_lds((gas_us)(gB + k0),          ldsB0, 16, 0, 0);
    __builtin_amdgcn_global_load_lds((gas_us)(gB + k0 + rowoff), ldsB1, 16, 0, 0);
    __syncthreads();

    short8 af[4], bfr[4];
    #pragma unroll
    for (int i = 0; i < 4; i++) af[i]  = Asm8[quad * BM + wm + i * 16 + la];
    #pragma unroll
    for (int j = 0; j < 4; j++) bfr[j] = Bsm8[quad * BN + wn + j * 16 + la];

    #pragma unroll
    for (int i = 0; i < 4; i++)
      #pragma unroll
      for (int j = 0; j < 4; j++)
        acc[i][j] = __builtin_amdgcn_mfma_f32_16x16x32_bf16(af[i], bfr[j], acc[i][j], 0, 0, 0);

    __syncthreads();
  }

  // epilogue: C/D layout: n = lane&15, m = quad*4 + reg   [measured m89/m91]
  float* Cf = (float*)Cout + (long)bz * sC;
  unsigned short* Ch = (unsigned short*)Cout + (long)bz * sC;
  #pragma unroll
  for (int i = 0; i < 4; i++) {
    #pragma unroll
    for (int j = 0; j < 4; j++) {
      #pragma unroll
      for (int r = 0; r < 4; r++) {
        long m = m0 + wm + i * 16 + quad * 4 + r;
        long n = n0 + wn + j * 16 + la;
        float v = acc[i][j][r] * alpha;
        if (bias_mode == 1)      v += bias[n];
        else if (bias_mode == 2) v += bias[m];
        long idx = m * (long)ldc + n;
        if (out_fp32) Cf[idx] = v;
        else          Ch[idx] = f2bf(v);
      }
    }
  }
}

// ---------------- row softmax (in-place, bf16) ----------------
__global__ __launch_bounds__(256) void softmax_rows(unsigned short* __restrict__ S, int cols){
  long row = blockIdx.x;
  unsigned short* p = S + row * (long)cols;
  int tid  = threadIdx.x;
  int wave = tid >> 6;
  int lane = tid & 63;

  uint4 raw = ((const uint4*)p)[tid];   // 8 bf16
  unsigned short* rs = (unsigned short*)&raw;
  float x[8];
  float mx = -1e30f;
  #pragma unroll
  for (int i = 0; i < 8; i++) { x[i] = bf2f(rs[i]); mx = fmaxf(mx, x[i]); }
  #pragma unroll
  for (int off = 32; off >= 1; off >>= 1) mx = fmaxf(mx, __shfl_xor(mx, off, 64));

  __shared__ float smax[4], ssum[4];
  if (lane == 0) smax[wave] = mx;
  __syncthreads();
  mx = fmaxf(fmaxf(smax[0], smax[1]), fmaxf(smax[2], smax[3]));

  float s = 0.0f;
  #pragma unroll
  for (int i = 0; i < 8; i++) { x[i] = __expf(x[i] - mx); s += x[i]; }
  #pragma unroll
  for (int off = 32; off >= 1; off >>= 1) s += __shfl_xor(s, off, 64);
  if (lane == 0) ssum[wave] = s;
  __syncthreads();
  s = ssum[0] + ssum[1] + ssum[2] + ssum[3];
  float inv = 1.0f / s;

  #pragma unroll
  for (int i = 0; i < 8; i++) rs[i] = f2bf(x[i] * inv);
  ((uint4*)p)[tid] = raw;
}

// ---------------- launch ----------------

extern "C" void kernel_launch(void* const* d_in, const int* in_sizes, int n_in,
                              void* d_out, int out_size, void* d_ws, size_t ws_size,
                              hipStream_t stream)
{
  const float* x  = (const float*)d_in[0];
  const float* Wq = (const float*)d_in[1];
  const float* bq = (const float*)d_in[2];
  const float* Wk = (const float*)d_in[3];
  const float* bk = (const float*)d_in[4];
  const float* Wv = (const float*)d_in[5];
  const float* bv = (const float*)d_in[6];
  const float* Wo = (const float*)d_in[7];
  const float* bo = (const float*)d_in[8];

  const int B = 8, S = 2048, E = 768;
  const long BS = (long)B * S;   // 16384

  char* ws = (char*)d_ws;
  unsigned short* x_bf = (unsigned short*)ws;  ws += BS * E * 2;     // 25.2 MB (also ctx)
  unsigned short* Wqt  = (unsigned short*)ws;  ws += (long)E * E * 2;
  unsigned short* Wkt  = (unsigned short*)ws;  ws += (long)E * E * 2;
  unsigned short* Wvt  = (unsigned short*)ws;  ws += (long)E * E * 2;
  unsigned short* Wot  = (unsigned short*)ws;  ws += (long)E * E * 2;
  unsigned short* Qb   = (unsigned short*)ws;  ws += BS * E * 2;     // 25.2 MB
  unsigned short* Kb   = (unsigned short*)ws;  ws += BS * E * 2;     // 25.2 MB
  unsigned short* Vt   = (unsigned short*)ws;  ws += BS * E * 2;     // 25.2 MB  [B][E][S]
  unsigned short* Sb   = (unsigned short*)ws;  ws += (long)B * S * S * 2; // 67.1 MB
  unsigned short* Cx   = x_bf;  // ctx aliases x_bf (x_bf dead after Vt gemm)

  if (ws_size < (size_t)((char*)ws - (char*)d_ws)) return;

  const float rsE = 1.0f / sqrtf((float)E);

  cast_f32_bf16<<<(int)((BS * E) / 1024), 256, 0, stream>>>(x, x_bf, BS * E);
  dim3 tg(E / 64, E / 64);
  transpose_cast_w<<<tg, 256, 0, stream>>>(Wq, Wqt, E);
  transpose_cast_w<<<tg, 256, 0, stream>>>(Wk, Wkt, E);
  transpose_cast_w<<<tg, 256, 0, stream>>>(Wv, Wvt, E);
  transpose_cast_w<<<tg, 256, 0, stream>>>(Wo, Wot, E);

  dim3 g1(E / BN, BS / BM, 1);
  gemm_bt<<<g1, 256, 0, stream>>>(x_bf, Wqt, Qb, bq, (int)BS, E, E, E, 0, 0, 0, 1.0f, 1, 0);
  gemm_bt<<<g1, 256, 0, stream>>>(x_bf, Wkt, Kb, bk, (int)BS, E, E, E, 0, 0, 0, 1.0f, 1, 0);

  dim3 gv(S / BN, E / BM, B);
  gemm_bt<<<gv, 256, 0, stream>>>(Wvt, x_bf, Vt, bv, E, S, E, S,
                                  0, (long)S * E, (long)E * S, 1.0f, 2, 0);

  dim3 gs(S / BN, S / BM, B);
  gemm_bt<<<gs, 256, 0, stream>>>(Qb, Kb, Sb, nullptr, S, S, E, S,
                                  (long)S * E, (long)S * E, (long)S * S, rsE, 0, 0);

  softmax_rows<<<(int)BS, 256, 0, stream>>>(Sb, S);

  dim3 gp(E / BN, S / BM, B);
  gemm_bt<<<gp, 256, 0, stream>>>(Sb, Vt, Cx, nullptr, S, E, S, E,
                                  (long)S * S, (long)E * S, (long)S * E, 1.0f, 0, 0);

  gemm_bt<<<g1, 256, 0, stream>>>(Cx, Wot, (float*)d_out, bo, (int)BS, E, E, E,
                                  0, 0, 0, 1.0f, 1, 1);
}

// Round 3
// 510.298 us; speedup vs baseline: 1.1889x; 1.1889x over previous
//
#include <hip/hip_runtime.h>
#include <hip/hip_bf16.h>

// Single-head self-attention, B=8 S=2048 E=768, fp32 in/out.
// R3: m97-style global_load_lds staging with COALESCED addresses.
//   LDS tile row-major [128 rows][32 k] (64B/row). One global_load_lds covers
//   16 rows (lanes 4g..4g+3 share a 64B row segment -> coalesced).
//   XOR swizzle on the GLOBAL side breaks MFMA-read bank conflicts:
//     lane i fetches global chunk (i&3)^((i>>3)&3)  -> LDS[r][p] holds chunk p^((r>>1)&3)
//     fragment read: chunk position quad^((la>>1)&3) -> 1 access/bank/phase.

using short8  = __attribute__((ext_vector_type(8))) short;
using floatx4 = __attribute__((ext_vector_type(4))) float;

typedef const __attribute__((address_space(1))) unsigned short* gas_us;
typedef __attribute__((address_space(3))) unsigned short* las_us;

__device__ __forceinline__ float bf2f(unsigned short u){
  union { unsigned int i; float f; } v; v.i = ((unsigned int)u) << 16; return v.f;
}
__device__ __forceinline__ unsigned short f2bf(float f){
  union { float f; unsigned int i; } v; v.f = f;
  unsigned int r = v.i + 0x7fffu + ((v.i >> 16) & 1u);   // RNE
  return (unsigned short)(r >> 16);
}

// ---------------- prep kernels ----------------

__global__ __launch_bounds__(256) void cast_f32_bf16(const float* __restrict__ in,
                                                     unsigned short* __restrict__ out,
                                                     long n){
  long i = ((long)blockIdx.x * 256 + threadIdx.x) * 4;
  if (i + 3 < n) {
    float4 v = *(const float4*)(in + i);
    uint2 o;
    o.x = (unsigned int)f2bf(v.x) | ((unsigned int)f2bf(v.y) << 16);
    o.y = (unsigned int)f2bf(v.z) | ((unsigned int)f2bf(v.w) << 16);
    *(uint2*)(out + i) = o;
  }
}

// W [n x n] fp32 row-major -> Wt [n x n] bf16, Wt[f][e] = W[e][f]
__global__ __launch_bounds__(256) void transpose_cast_w(const float* __restrict__ W,
                                                        unsigned short* __restrict__ Wt,
                                                        int n){
  __shared__ float tile[64][65];
  int bx = blockIdx.x * 64;     // f base
  int by = blockIdx.y * 64;     // e base
  int tx = threadIdx.x & 63;
  int ty = threadIdx.x >> 6;    // 0..3
  #pragma unroll
  for (int r = ty; r < 64; r += 4)
    tile[r][tx] = W[(long)(by + r) * n + bx + tx];
  __syncthreads();
  #pragma unroll
  for (int r = ty; r < 64; r += 4)
    Wt[(long)(bx + r) * n + by + tx] = f2bf(tile[tx][r]);
}

// ---------------- tiled MFMA GEMM ----------------
// C[m,n] = alpha * sum_k A[m,k]*Bt[n,k]  (+ bias)
// A  : bf16 [M,K] row-major (batch stride sA elements)
// Bt : bf16 [N,K] row-major (batch stride sB elements)
// C  : bf16 or fp32, ldc leading dim (batch stride sC elements)
// M,N multiples of 128; K multiple of 32. No bounds checks.

#define BM 128
#define BN 128
#define BK 32

__global__ __launch_bounds__(256) void gemm_bt(
    const unsigned short* __restrict__ A,
    const unsigned short* __restrict__ Bt,
    void* __restrict__ Cout,
    const float* __restrict__ bias,
    int M, int N, int K, int ldc,
    long sA, long sB, long sC,
    float alpha, int bias_mode, int out_fp32)
{
  const int bz = blockIdx.z;
  A  += (long)bz * sA;
  Bt += (long)bz * sB;

  // row-major LDS tile: [row 0..127][32 k shorts] (chunk-swizzled, see header)
  __shared__ __align__(16) unsigned short Asm[BM * BK];
  __shared__ __align__(16) unsigned short Bsm[BN * BK];

  const int tid  = threadIdx.x;
  const int wave = tid >> 6;
  const int lane = tid & 63;
  const int la   = lane & 15;
  const int quad = lane >> 4;
  const int wm = (wave & 1) * 64;
  const int wn = (wave >> 1) * 64;
  const int sw = (la >> 1) & 3;          // read-side swizzle

  const long m0 = (long)blockIdx.y * BM;
  const long n0 = (long)blockIdx.x * BN;

  // staging: wave w stages rows w*32 .. w*32+31 (two instrs of 16 rows each).
  // lane i: row offset i>>2, fetches global chunk (i&3)^((i>>3)&3).
  const int rlo = lane >> 2;                         // 0..15
  const int cg  = (lane & 3) ^ ((lane >> 3) & 3);    // swizzled global chunk
  const unsigned short* gA = A  + (m0 + wave * 32 + rlo) * (long)K + cg * 8;
  const unsigned short* gB = Bt + (n0 + wave * 32 + rlo) * (long)K + cg * 8;
  las_us lA0 = (las_us)&Asm[(wave * 32 +  0) * BK];
  las_us lA1 = (las_us)&Asm[(wave * 32 + 16) * BK];
  las_us lB0 = (las_us)&Bsm[(wave * 32 +  0) * BK];
  las_us lB1 = (las_us)&Bsm[(wave * 32 + 16) * BK];
  const long h16 = 16 * (long)K;

  floatx4 acc[4][4];
  #pragma unroll
  for (int i = 0; i < 4; i++)
    #pragma unroll
    for (int j = 0; j < 4; j++)
      #pragma unroll
      for (int r = 0; r < 4; r++) acc[i][j][r] = 0.0f;

  const short8* Asm8 = (const short8*)Asm;   // index: row*4 + chunk
  const short8* Bsm8 = (const short8*)Bsm;

  for (int k0 = 0; k0 < K; k0 += BK) {
    __builtin_amdgcn_global_load_lds((gas_us)(gA + k0),       lA0, 16, 0, 0);
    __builtin_amdgcn_global_load_lds((gas_us)(gA + k0 + h16), lA1, 16, 0, 0);
    __builtin_amdgcn_global_load_lds((gas_us)(gB + k0),       lB0, 16, 0, 0);
    __builtin_amdgcn_global_load_lds((gas_us)(gB + k0 + h16), lB1, 16, 0, 0);
    __syncthreads();

    short8 af[4], bfr[4];
    #pragma unroll
    for (int i = 0; i < 4; i++)
      af[i]  = Asm8[(wm + i * 16 + la) * 4 + (quad ^ sw)];
    #pragma unroll
    for (int j = 0; j < 4; j++)
      bfr[j] = Bsm8[(wn + j * 16 + la) * 4 + (quad ^ sw)];

    #pragma unroll
    for (int i = 0; i < 4; i++)
      #pragma unroll
      for (int j = 0; j < 4; j++)
        acc[i][j] = __builtin_amdgcn_mfma_f32_16x16x32_bf16(af[i], bfr[j], acc[i][j], 0, 0, 0);

    __syncthreads();
  }

  // epilogue: C/D layout: n = lane&15, m = quad*4 + reg   [measured m89/m91]
  float* Cf = (float*)Cout + (long)bz * sC;
  unsigned short* Ch = (unsigned short*)Cout + (long)bz * sC;
  #pragma unroll
  for (int i = 0; i < 4; i++) {
    #pragma unroll
    for (int j = 0; j < 4; j++) {
      #pragma unroll
      for (int r = 0; r < 4; r++) {
        long m = m0 + wm + i * 16 + quad * 4 + r;
        long n = n0 + wn + j * 16 + la;
        float v = acc[i][j][r] * alpha;
        if (bias_mode == 1)      v += bias[n];
        else if (bias_mode == 2) v += bias[m];
        long idx = m * (long)ldc + n;
        if (out_fp32) Cf[idx] = v;
        else          Ch[idx] = f2bf(v);
      }
    }
  }
}

// ---------------- row softmax (in-place, bf16) ----------------
__global__ __launch_bounds__(256) void softmax_rows(unsigned short* __restrict__ S, int cols){
  long row = blockIdx.x;
  unsigned short* p = S + row * (long)cols;
  int tid  = threadIdx.x;
  int wave = tid >> 6;
  int lane = tid & 63;

  uint4 raw = ((const uint4*)p)[tid];   // 8 bf16
  unsigned short* rs = (unsigned short*)&raw;
  float x[8];
  float mx = -1e30f;
  #pragma unroll
  for (int i = 0; i < 8; i++) { x[i] = bf2f(rs[i]); mx = fmaxf(mx, x[i]); }
  #pragma unroll
  for (int off = 32; off >= 1; off >>= 1) mx = fmaxf(mx, __shfl_xor(mx, off, 64));

  __shared__ float smax[4], ssum[4];
  if (lane == 0) smax[wave] = mx;
  __syncthreads();
  mx = fmaxf(fmaxf(smax[0], smax[1]), fmaxf(smax[2], smax[3]));

  float s = 0.0f;
  #pragma unroll
  for (int i = 0; i < 8; i++) { x[i] = __expf(x[i] - mx); s += x[i]; }
  #pragma unroll
  for (int off = 32; off >= 1; off >>= 1) s += __shfl_xor(s, off, 64);
  if (lane == 0) ssum[wave] = s;
  __syncthreads();
  s = ssum[0] + ssum[1] + ssum[2] + ssum[3];
  float inv = 1.0f / s;

  #pragma unroll
  for (int i = 0; i < 8; i++) rs[i] = f2bf(x[i] * inv);
  ((uint4*)p)[tid] = raw;
}

// ---------------- launch ----------------

extern "C" void kernel_launch(void* const* d_in, const int* in_sizes, int n_in,
                              void* d_out, int out_size, void* d_ws, size_t ws_size,
                              hipStream_t stream)
{
  const float* x  = (const float*)d_in[0];
  const float* Wq = (const float*)d_in[1];
  const float* bq = (const float*)d_in[2];
  const float* Wk = (const float*)d_in[3];
  const float* bk = (const float*)d_in[4];
  const float* Wv = (const float*)d_in[5];
  const float* bv = (const float*)d_in[6];
  const float* Wo = (const float*)d_in[7];
  const float* bo = (const float*)d_in[8];

  const int B = 8, S = 2048, E = 768;
  const long BS = (long)B * S;   // 16384

  char* ws = (char*)d_ws;
  unsigned short* x_bf = (unsigned short*)ws;  ws += BS * E * 2;     // 25.2 MB (also ctx)
  unsigned short* Wqt  = (unsigned short*)ws;  ws += (long)E * E * 2;
  unsigned short* Wkt  = (unsigned short*)ws;  ws += (long)E * E * 2;
  unsigned short* Wvt  = (unsigned short*)ws;  ws += (long)E * E * 2;
  unsigned short* Wot  = (unsigned short*)ws;  ws += (long)E * E * 2;
  unsigned short* Qb   = (unsigned short*)ws;  ws += BS * E * 2;     // 25.2 MB
  unsigned short* Kb   = (unsigned short*)ws;  ws += BS * E * 2;     // 25.2 MB
  unsigned short* Vt   = (unsigned short*)ws;  ws += BS * E * 2;     // 25.2 MB  [B][E][S]
  unsigned short* Sb   = (unsigned short*)ws;  ws += (long)B * S * S * 2; // 67.1 MB
  unsigned short* Cx   = x_bf;  // ctx aliases x_bf (x_bf dead after Vt gemm)

  if (ws_size < (size_t)((char*)ws - (char*)d_ws)) return;

  const float rsE = 1.0f / sqrtf((float)E);

  cast_f32_bf16<<<(int)((BS * E) / 1024), 256, 0, stream>>>(x, x_bf, BS * E);
  dim3 tg(E / 64, E / 64);
  transpose_cast_w<<<tg, 256, 0, stream>>>(Wq, Wqt, E);
  transpose_cast_w<<<tg, 256, 0, stream>>>(Wk, Wkt, E);
  transpose_cast_w<<<tg, 256, 0, stream>>>(Wv, Wvt, E);
  transpose_cast_w<<<tg, 256, 0, stream>>>(Wo, Wot, E);

  dim3 g1(E / BN, BS / BM, 1);
  gemm_bt<<<g1, 256, 0, stream>>>(x_bf, Wqt, Qb, bq, (int)BS, E, E, E, 0, 0, 0, 1.0f, 1, 0);
  gemm_bt<<<g1, 256, 0, stream>>>(x_bf, Wkt, Kb, bk, (int)BS, E, E, E, 0, 0, 0, 1.0f, 1, 0);

  dim3 gv(S / BN, E / BM, B);
  gemm_bt<<<gv, 256, 0, stream>>>(Wvt, x_bf, Vt, bv, E, S, E, S,
                                  0, (long)S * E, (long)E * S, 1.0f, 2, 0);

  dim3 gs(S / BN, S / BM, B);
  gemm_bt<<<gs, 256, 0, stream>>>(Qb, Kb, Sb, nullptr, S, S, E, S,
                                  (long)S * E, (long)S * E, (long)S * S, rsE, 0, 0);

  softmax_rows<<<(int)BS, 256, 0, stream>>>(Sb, S);

  dim3 gp(E / BN, S / BM, B);
  gemm_bt<<<gp, 256, 0, stream>>>(Sb, Vt, Cx, nullptr, S, E, S, E,
                                  (long)S * S, (long)E * S, (long)S * E, 1.0f, 0, 0);

  gemm_bt<<<g1, 256, 0, stream>>>(Cx, Wot, (float*)d_out, bo, (int)BS, E, E, E,
                                  0, 0, 0, 1.0f, 1, 1);
}

// Round 4
// 498.497 us; speedup vs baseline: 1.2171x; 1.0237x over previous
//
#include <hip/hip_runtime.h>
#include <hip/hip_bf16.h>

// Single-head self-attention, B=8 S=2048 E=768, fp32 in/out.
// R4: R3 + double-buffered LDS with EARLY prefetch issue + single barrier/iter.
//   K-loop: barrier -> issue DMA(tile k+1 -> buf^1) -> ds_read+MFMA on buf.
//   The barrier at iter k+1 drains a DMA issued one full compute phase earlier,
//   so its implicit vmcnt(0) is cheap (vs m97 structure: DMA issued right
//   before the consuming barrier = full latency exposed every iteration).
//   WAR safe: top barrier implies each wave drained its ds_reads (lgkmcnt).

using short8  = __attribute__((ext_vector_type(8))) short;
using floatx4 = __attribute__((ext_vector_type(4))) float;

typedef const __attribute__((address_space(1))) unsigned short* gas_us;
typedef __attribute__((address_space(3))) unsigned short* las_us;

__device__ __forceinline__ float bf2f(unsigned short u){
  union { unsigned int i; float f; } v; v.i = ((unsigned int)u) << 16; return v.f;
}
__device__ __forceinline__ unsigned short f2bf(float f){
  union { float f; unsigned int i; } v; v.f = f;
  unsigned int r = v.i + 0x7fffu + ((v.i >> 16) & 1u);   // RNE
  return (unsigned short)(r >> 16);
}

// ---------------- prep kernels ----------------

__global__ __launch_bounds__(256) void cast_f32_bf16(const float* __restrict__ in,
                                                     unsigned short* __restrict__ out,
                                                     long n){
  long i = ((long)blockIdx.x * 256 + threadIdx.x) * 4;
  if (i + 3 < n) {
    float4 v = *(const float4*)(in + i);
    uint2 o;
    o.x = (unsigned int)f2bf(v.x) | ((unsigned int)f2bf(v.y) << 16);
    o.y = (unsigned int)f2bf(v.z) | ((unsigned int)f2bf(v.w) << 16);
    *(uint2*)(out + i) = o;
  }
}

// W [n x n] fp32 row-major -> Wt [n x n] bf16, Wt[f][e] = W[e][f]
__global__ __launch_bounds__(256) void transpose_cast_w(const float* __restrict__ W,
                                                        unsigned short* __restrict__ Wt,
                                                        int n){
  __shared__ float tile[64][65];
  int bx = blockIdx.x * 64;     // f base
  int by = blockIdx.y * 64;     // e base
  int tx = threadIdx.x & 63;
  int ty = threadIdx.x >> 6;    // 0..3
  #pragma unroll
  for (int r = ty; r < 64; r += 4)
    tile[r][tx] = W[(long)(by + r) * n + bx + tx];
  __syncthreads();
  #pragma unroll
  for (int r = ty; r < 64; r += 4)
    Wt[(long)(bx + r) * n + by + tx] = f2bf(tile[tx][r]);
}

// ---------------- tiled MFMA GEMM ----------------
// C[m,n] = alpha * sum_k A[m,k]*Bt[n,k]  (+ bias)
// A  : bf16 [M,K] row-major (batch stride sA elements)
// Bt : bf16 [N,K] row-major (batch stride sB elements)
// C  : bf16 or fp32, ldc leading dim (batch stride sC elements)
// M,N multiples of 128; K multiple of 32. No bounds checks.

#define BM 128
#define BN 128
#define BK 32

__global__ __launch_bounds__(256) void gemm_bt(
    const unsigned short* __restrict__ A,
    const unsigned short* __restrict__ Bt,
    void* __restrict__ Cout,
    const float* __restrict__ bias,
    int M, int N, int K, int ldc,
    long sA, long sB, long sC,
    float alpha, int bias_mode, int out_fp32)
{
  const int bz = blockIdx.z;
  A  += (long)bz * sA;
  Bt += (long)bz * sB;

  // double-buffered row-major tiles: [buf][row 0..127][32 k] (chunk-swizzled)
  __shared__ __align__(16) unsigned short Asm[2 * BM * BK];
  __shared__ __align__(16) unsigned short Bsm[2 * BN * BK];

  const int tid  = threadIdx.x;
  const int wave = tid >> 6;
  const int lane = tid & 63;
  const int la   = lane & 15;
  const int quad = lane >> 4;
  const int wm = (wave & 1) * 64;
  const int wn = (wave >> 1) * 64;
  const int sw = (la >> 1) & 3;          // read-side swizzle

  const long m0 = (long)blockIdx.y * BM;
  const long n0 = (long)blockIdx.x * BN;

  // staging: wave w stages rows w*32 .. w*32+31 (two instrs of 16 rows each).
  // lane i: row offset i>>2, fetches global chunk (i&3)^((i>>3)&3).
  // LDS[r][p] then holds global chunk p^((r>>1)&3); read at p = quad^sw.
  const int rlo = lane >> 2;                         // 0..15
  const int cg  = (lane & 3) ^ ((lane >> 3) & 3);    // swizzled global chunk
  const unsigned short* gA = A  + (m0 + wave * 32 + rlo) * (long)K + cg * 8;
  const unsigned short* gB = Bt + (n0 + wave * 32 + rlo) * (long)K + cg * 8;
  const long h16 = 16 * (long)K;
  const int ldsrow = (wave * 32) * BK;

  floatx4 acc[4][4];
  #pragma unroll
  for (int i = 0; i < 4; i++)
    #pragma unroll
    for (int j = 0; j < 4; j++)
      #pragma unroll
      for (int r = 0; r < 4; r++) acc[i][j][r] = 0.0f;

  // prologue: stage tile 0 into buffer 0
  __builtin_amdgcn_global_load_lds((gas_us)(gA),       (las_us)&Asm[ldsrow],           16, 0, 0);
  __builtin_amdgcn_global_load_lds((gas_us)(gA + h16), (las_us)&Asm[ldsrow + 16 * BK], 16, 0, 0);
  __builtin_amdgcn_global_load_lds((gas_us)(gB),       (las_us)&Bsm[ldsrow],           16, 0, 0);
  __builtin_amdgcn_global_load_lds((gas_us)(gB + h16), (las_us)&Bsm[ldsrow + 16 * BK], 16, 0, 0);

  int buf = 0;
  for (int k0 = 0; k0 < K; k0 += BK, buf ^= 1) {
    __syncthreads();   // publishes buf (prefetched a full compute phase ago)

    if (k0 + BK < K) {
      const int nb = (buf ^ 1) * BM * BK;
      __builtin_amdgcn_global_load_lds((gas_us)(gA + k0 + BK),       (las_us)&Asm[nb + ldsrow],           16, 0, 0);
      __builtin_amdgcn_global_load_lds((gas_us)(gA + k0 + BK + h16), (las_us)&Asm[nb + ldsrow + 16 * BK], 16, 0, 0);
      __builtin_amdgcn_global_load_lds((gas_us)(gB + k0 + BK),       (las_us)&Bsm[nb + ldsrow],           16, 0, 0);
      __builtin_amdgcn_global_load_lds((gas_us)(gB + k0 + BK + h16), (las_us)&Bsm[nb + ldsrow + 16 * BK], 16, 0, 0);
    }

    const short8* A8 = (const short8*)&Asm[buf * BM * BK];   // index: row*4 + chunk
    const short8* B8 = (const short8*)&Bsm[buf * BN * BK];

    short8 af[4], bfr[4];
    #pragma unroll
    for (int i = 0; i < 4; i++)
      af[i]  = A8[(wm + i * 16 + la) * 4 + (quad ^ sw)];
    #pragma unroll
    for (int j = 0; j < 4; j++)
      bfr[j] = B8[(wn + j * 16 + la) * 4 + (quad ^ sw)];

    #pragma unroll
    for (int i = 0; i < 4; i++)
      #pragma unroll
      for (int j = 0; j < 4; j++)
        acc[i][j] = __builtin_amdgcn_mfma_f32_16x16x32_bf16(af[i], bfr[j], acc[i][j], 0, 0, 0);
    // no second barrier: WAR on buf^1 protected by next iteration's top barrier
  }

  // epilogue: C/D layout: n = lane&15, m = quad*4 + reg   [measured m89/m91]
  float* Cf = (float*)Cout + (long)bz * sC;
  unsigned short* Ch = (unsigned short*)Cout + (long)bz * sC;
  #pragma unroll
  for (int i = 0; i < 4; i++) {
    #pragma unroll
    for (int j = 0; j < 4; j++) {
      #pragma unroll
      for (int r = 0; r < 4; r++) {
        long m = m0 + wm + i * 16 + quad * 4 + r;
        long n = n0 + wn + j * 16 + la;
        float v = acc[i][j][r] * alpha;
        if (bias_mode == 1)      v += bias[n];
        else if (bias_mode == 2) v += bias[m];
        long idx = m * (long)ldc + n;
        if (out_fp32) Cf[idx] = v;
        else          Ch[idx] = f2bf(v);
      }
    }
  }
}

// ---------------- row softmax (in-place, bf16) ----------------
__global__ __launch_bounds__(256) void softmax_rows(unsigned short* __restrict__ S, int cols){
  long row = blockIdx.x;
  unsigned short* p = S + row * (long)cols;
  int tid  = threadIdx.x;
  int wave = tid >> 6;
  int lane = tid & 63;

  uint4 raw = ((const uint4*)p)[tid];   // 8 bf16
  unsigned short* rs = (unsigned short*)&raw;
  float x[8];
  float mx = -1e30f;
  #pragma unroll
  for (int i = 0; i < 8; i++) { x[i] = bf2f(rs[i]); mx = fmaxf(mx, x[i]); }
  #pragma unroll
  for (int off = 32; off >= 1; off >>= 1) mx = fmaxf(mx, __shfl_xor(mx, off, 64));

  __shared__ float smax[4], ssum[4];
  if (lane == 0) smax[wave] = mx;
  __syncthreads();
  mx = fmaxf(fmaxf(smax[0], smax[1]), fmaxf(smax[2], smax[3]));

  float s = 0.0f;
  #pragma unroll
  for (int i = 0; i < 8; i++) { x[i] = __expf(x[i] - mx); s += x[i]; }
  #pragma unroll
  for (int off = 32; off >= 1; off >>= 1) s += __shfl_xor(s, off, 64);
  if (lane == 0) ssum[wave] = s;
  __syncthreads();
  s = ssum[0] + ssum[1] + ssum[2] + ssum[3];
  float inv = 1.0f / s;

  #pragma unroll
  for (int i = 0; i < 8; i++) rs[i] = f2bf(x[i] * inv);
  ((uint4*)p)[tid] = raw;
}

// ---------------- launch ----------------

extern "C" void kernel_launch(void* const* d_in, const int* in_sizes, int n_in,
                              void* d_out, int out_size, void* d_ws, size_t ws_size,
                              hipStream_t stream)
{
  const float* x  = (const float*)d_in[0];
  const float* Wq = (const float*)d_in[1];
  const float* bq = (const float*)d_in[2];
  const float* Wk = (const float*)d_in[3];
  const float* bk = (const float*)d_in[4];
  const float* Wv = (const float*)d_in[5];
  const float* bv = (const float*)d_in[6];
  const float* Wo = (const float*)d_in[7];
  const float* bo = (const float*)d_in[8];

  const int B = 8, S = 2048, E = 768;
  const long BS = (long)B * S;   // 16384

  char* ws = (char*)d_ws;
  unsigned short* x_bf = (unsigned short*)ws;  ws += BS * E * 2;     // 25.2 MB (also ctx)
  unsigned short* Wqt  = (unsigned short*)ws;  ws += (long)E * E * 2;
  unsigned short* Wkt  = (unsigned short*)ws;  ws += (long)E * E * 2;
  unsigned short* Wvt  = (unsigned short*)ws;  ws += (long)E * E * 2;
  unsigned short* Wot  = (unsigned short*)ws;  ws += (long)E * E * 2;
  unsigned short* Qb   = (unsigned short*)ws;  ws += BS * E * 2;     // 25.2 MB
  unsigned short* Kb   = (unsigned short*)ws;  ws += BS * E * 2;     // 25.2 MB
  unsigned short* Vt   = (unsigned short*)ws;  ws += BS * E * 2;     // 25.2 MB  [B][E][S]
  unsigned short* Sb   = (unsigned short*)ws;  ws += (long)B * S * S * 2; // 67.1 MB
  unsigned short* Cx   = x_bf;  // ctx aliases x_bf (x_bf dead after Vt gemm)

  if (ws_size < (size_t)((char*)ws - (char*)d_ws)) return;

  const float rsE = 1.0f / sqrtf((float)E);

  cast_f32_bf16<<<(int)((BS * E) / 1024), 256, 0, stream>>>(x, x_bf, BS * E);
  dim3 tg(E / 64, E / 64);
  transpose_cast_w<<<tg, 256, 0, stream>>>(Wq, Wqt, E);
  transpose_cast_w<<<tg, 256, 0, stream>>>(Wk, Wkt, E);
  transpose_cast_w<<<tg, 256, 0, stream>>>(Wv, Wvt, E);
  transpose_cast_w<<<tg, 256, 0, stream>>>(Wo, Wot, E);

  dim3 g1(E / BN, BS / BM, 1);
  gemm_bt<<<g1, 256, 0, stream>>>(x_bf, Wqt, Qb, bq, (int)BS, E, E, E, 0, 0, 0, 1.0f, 1, 0);
  gemm_bt<<<g1, 256, 0, stream>>>(x_bf, Wkt, Kb, bk, (int)BS, E, E, E, 0, 0, 0, 1.0f, 1, 0);

  dim3 gv(S / BN, E / BM, B);
  gemm_bt<<<gv, 256, 0, stream>>>(Wvt, x_bf, Vt, bv, E, S, E, S,
                                  0, (long)S * E, (long)E * S, 1.0f, 2, 0);

  dim3 gs(S / BN, S / BM, B);
  gemm_bt<<<gs, 256, 0, stream>>>(Qb, Kb, Sb, nullptr, S, S, E, S,
                                  (long)S * E, (long)S * E, (long)S * S, rsE, 0, 0);

  softmax_rows<<<(int)BS, 256, 0, stream>>>(Sb, S);

  dim3 gp(E / BN, S / BM, B);
  gemm_bt<<<gp, 256, 0, stream>>>(Sb, Vt, Cx, nullptr, S, E, S, E,
                                  (long)S * S, (long)E * S, (long)S * E, 1.0f, 0, 0);

  gemm_bt<<<g1, 256, 0, stream>>>(Cx, Wot, (float*)d_out, bo, (int)BS, E, E, E,
                                  0, 0, 0, 1.0f, 1, 1);
}